// Round 1
// baseline (341.804 us; speedup 1.0000x reference)
//
#include <hip/hip_runtime.h>
#include <hip/hip_bf16.h>
#include <math.h>

// SGNS (skip-gram negative sampling) loss.
// V=100000, D=128, N=262144, K=5.
// One 64-lane wave per pair: lane l holds float2 = row elements [2l, 2l+1].
// 7 gathered rows (1 from emb, 6 from out_w), 6 dots, 6 wave reductions.

#define D 128
#define K 5

__device__ __forceinline__ float log_sigmoid(float x) {
    // log(sigmoid(x)) = min(x,0) - log1p(exp(-|x|)) — numerically stable.
    return fminf(x, 0.0f) - log1pf(__expf(-fabsf(x)));
}

__global__ __launch_bounds__(256) void sgns_kernel(
    const float* __restrict__ emb,
    const float* __restrict__ out_w,
    const int* __restrict__ tgt_ids,
    const int* __restrict__ ctx_ids,
    const int* __restrict__ neg_ids,
    float* __restrict__ out,
    int N)
{
    const int lane = threadIdx.x & 63;
    const int wave = threadIdx.x >> 6;
    const int n = blockIdx.x * (blockDim.x >> 6) + wave;
    if (n >= N) return;

    // Gather input embedding row (wave-uniform row index).
    const int t = tgt_ids[n];
    const float2 in = ((const float2*)(emb + (size_t)t * D))[lane];

    // 6 output rows: [ctx, neg0..neg4]
    int rows[K + 1];
    rows[0] = ctx_ids[n];
#pragma unroll
    for (int k = 0; k < K; ++k) rows[k + 1] = neg_ids[(size_t)n * K + k];

    // Partial dot per row (2 elements per lane). Issue all 6 loads first
    // for memory-level parallelism, then FMA.
    float2 wv[K + 1];
#pragma unroll
    for (int j = 0; j < K + 1; ++j)
        wv[j] = ((const float2*)(out_w + (size_t)rows[j] * D))[lane];

    float partial[K + 1];
#pragma unroll
    for (int j = 0; j < K + 1; ++j)
        partial[j] = in.x * wv[j].x + in.y * wv[j].y;

    // Butterfly reduce each of the 6 partials across the 64-lane wave.
#pragma unroll
    for (int j = 0; j < K + 1; ++j) {
        float v = partial[j];
#pragma unroll
        for (int off = 32; off > 0; off >>= 1)
            v += __shfl_xor(v, off, 64);
        partial[j] = v;
    }

    if (lane == 0) {
        float loss = log_sigmoid(partial[0]);      // positive score
#pragma unroll
        for (int k = 1; k < K + 1; ++k)
            loss += log_sigmoid(-partial[k]);      // negative scores
        out[n] = -loss;
    }
}

extern "C" void kernel_launch(void* const* d_in, const int* in_sizes, int n_in,
                              void* d_out, int out_size, void* d_ws, size_t ws_size,
                              hipStream_t stream) {
    const float* emb     = (const float*)d_in[0];
    const float* out_w   = (const float*)d_in[1];
    const int*   tgt_ids = (const int*)d_in[2];
    const int*   ctx_ids = (const int*)d_in[3];
    const int*   neg_ids = (const int*)d_in[4];
    float* out = (float*)d_out;

    const int N = in_sizes[2];           // 262144 pairs
    const int waves_per_block = 4;       // 256 threads
    const int blocks = (N + waves_per_block - 1) / waves_per_block;

    sgns_kernel<<<blocks, 256, 0, stream>>>(emb, out_w, tgt_ids, ctx_ids,
                                            neg_ids, out, N);
}

// Round 2
// 226.893 us; speedup vs baseline: 1.5065x; 1.5065x over previous
//
#include <hip/hip_runtime.h>
#include <hip/hip_bf16.h>
#include <math.h>

// SGNS (skip-gram negative sampling) loss.
// V=100000, D=128, N=262144, K=5.
// 4 pairs per 64-lane wave: 16 lanes per pair, 8 floats per lane (2x float4).
// Cuts reduction cost from 6 steps/row (width 64) to 4 steps/row (width 16)
// and amortizes the instruction stream over 4 pairs.

#define D 128
#define K 5

__device__ __forceinline__ float log_sigmoid(float x) {
    // log(sigmoid(x)) = min(x,0) - log1p(exp(-|x|)) — numerically stable.
    return fminf(x, 0.0f) - log1pf(__expf(-fabsf(x)));
}

__global__ __launch_bounds__(256) void sgns_kernel(
    const float* __restrict__ emb,
    const float* __restrict__ out_w,
    const int* __restrict__ tgt_ids,
    const int* __restrict__ ctx_ids,
    const int* __restrict__ neg_ids,
    float* __restrict__ out,
    int N)
{
    const int lane = threadIdx.x & 63;
    const int wave = threadIdx.x >> 6;
    const int lg   = lane & 15;        // lane within 16-lane group
    const int grp  = lane >> 4;        // group (pair slot) within wave, 0..3
    const int n = (blockIdx.x * 4 + wave) * 4 + grp;   // pair id
    if (n >= N) return;

    // Indices for this pair (redundant across the 16 group lanes; L1 hits).
    const int t = tgt_ids[n];
    int rows[K + 1];
    rows[0] = ctx_ids[n];
    const int4 n4 = *(const int4*)(neg_ids + (size_t)n * K);
    rows[1] = n4.x; rows[2] = n4.y; rows[3] = n4.z; rows[4] = n4.w;
    rows[5] = neg_ids[(size_t)n * K + 4];

    // Input embedding row: lane lg holds elements [lg*4, lg*4+4) and
    // [64+lg*4, 64+lg*4+4) — each float4 load is 256 B contiguous per group.
    const float4* er = (const float4*)(emb + (size_t)t * D);
    const float4 in0 = er[lg];
    const float4 in1 = er[lg + 16];

    // Issue all 12 row loads first for memory-level parallelism.
    float4 w0[K + 1], w1[K + 1];
#pragma unroll
    for (int j = 0; j < K + 1; ++j) {
        const float4* wr = (const float4*)(out_w + (size_t)rows[j] * D);
        w0[j] = wr[lg];
        w1[j] = wr[lg + 16];
    }

    float dot[K + 1];
#pragma unroll
    for (int j = 0; j < K + 1; ++j) {
        dot[j] = in0.x * w0[j].x + in0.y * w0[j].y
               + in0.z * w0[j].z + in0.w * w0[j].w
               + in1.x * w1[j].x + in1.y * w1[j].y
               + in1.z * w1[j].z + in1.w * w1[j].w;
    }

    // Butterfly reduce within each 16-lane group (xor 1,2,4,8 never crosses
    // the group boundary).
#pragma unroll
    for (int j = 0; j < K + 1; ++j) {
        float v = dot[j];
        v += __shfl_xor(v, 1);
        v += __shfl_xor(v, 2);
        v += __shfl_xor(v, 4);
        v += __shfl_xor(v, 8);
        dot[j] = v;
    }

    if (lg == 0) {
        float loss = log_sigmoid(dot[0]);      // positive score
#pragma unroll
        for (int j = 1; j < K + 1; ++j)
            loss += log_sigmoid(-dot[j]);      // negative scores
        out[n] = -loss;
    }
}

extern "C" void kernel_launch(void* const* d_in, const int* in_sizes, int n_in,
                              void* d_out, int out_size, void* d_ws, size_t ws_size,
                              hipStream_t stream) {
    const float* emb     = (const float*)d_in[0];
    const float* out_w   = (const float*)d_in[1];
    const int*   tgt_ids = (const int*)d_in[2];
    const int*   ctx_ids = (const int*)d_in[3];
    const int*   neg_ids = (const int*)d_in[4];
    float* out = (float*)d_out;

    const int N = in_sizes[2];           // 262144 pairs
    const int pairs_per_block = 16;      // 4 waves x 4 pairs
    const int blocks = (N + pairs_per_block - 1) / pairs_per_block;

    sgns_kernel<<<blocks, 256, 0, stream>>>(emb, out_w, tgt_ids, ctx_ids,
                                            neg_ids, out, N);
}

// Round 3
// 204.919 us; speedup vs baseline: 1.6680x; 1.1072x over previous
//
#include <hip/hip_runtime.h>
#include <hip/hip_fp16.h>
#include <math.h>

// SGNS (skip-gram negative sampling) loss.  V=100000, D=128, N=262144, K=5.
//
// R3: tables converted to fp16 in d_ws each call (threshold 2.78, fp32 run
// measured absmax 0.25 — plenty of headroom). Gather kernel is VMEM-latency
// bound, so halving gathered bytes halves the per-pair VMEM instruction
// count: one fp16 row (256 B) = one dwordx4 per 16-lane group.
// Dot products accumulate in fp32 via v_dot2_f32_f16.

#define D 128
#define K 5

typedef _Float16 h2 __attribute__((ext_vector_type(2)));

__device__ __forceinline__ float log_sigmoid(float x) {
    return fminf(x, 0.0f) - log1pf(__expf(-fabsf(x)));
}

__device__ __forceinline__ float dot8_f16(uint4 a, uint4 b, float acc) {
#if __has_builtin(__builtin_amdgcn_fdot2)
    acc = __builtin_amdgcn_fdot2(__builtin_bit_cast(h2, a.x),
                                 __builtin_bit_cast(h2, b.x), acc, false);
    acc = __builtin_amdgcn_fdot2(__builtin_bit_cast(h2, a.y),
                                 __builtin_bit_cast(h2, b.y), acc, false);
    acc = __builtin_amdgcn_fdot2(__builtin_bit_cast(h2, a.z),
                                 __builtin_bit_cast(h2, b.z), acc, false);
    acc = __builtin_amdgcn_fdot2(__builtin_bit_cast(h2, a.w),
                                 __builtin_bit_cast(h2, b.w), acc, false);
#else
    const unsigned* au = (const unsigned*)&a;
    const unsigned* bu = (const unsigned*)&b;
#pragma unroll
    for (int i = 0; i < 4; ++i) {
        h2 ha = __builtin_bit_cast(h2, au[i]);
        h2 hb = __builtin_bit_cast(h2, bu[i]);
        acc += (float)ha.x * (float)hb.x + (float)ha.y * (float)hb.y;
    }
#endif
    return acc;
}

// ---- fp32 -> fp16 table conversion (streamed, ~6 TB/s) -------------------
struct H8 { __half2 a, b, c, d; };

__global__ __launch_bounds__(256) void cvt_f16_kernel(
    const float* __restrict__ src, __half* __restrict__ dst, int n /*floats*/)
{
    int i = (blockIdx.x * blockDim.x + threadIdx.x) * 8;
    if (i >= n) return;
    float4 x = *(const float4*)(src + i);
    float4 y = *(const float4*)(src + i + 4);
    H8 h;
    h.a = __floats2half2_rn(x.x, x.y);
    h.b = __floats2half2_rn(x.z, x.w);
    h.c = __floats2half2_rn(y.x, y.y);
    h.d = __floats2half2_rn(y.z, y.w);
    *(H8*)(dst + i) = h;
}

// ---- fp16 gather kernel: 16 lanes/pair, 4 pairs/wave ---------------------
__global__ __launch_bounds__(256, 8) void sgns_f16_kernel(
    const __half* __restrict__ embh,
    const __half* __restrict__ outh,
    const int* __restrict__ tgt_ids,
    const int* __restrict__ ctx_ids,
    const int* __restrict__ neg_ids,
    float* __restrict__ out,
    int N)
{
    const int lane = threadIdx.x & 63;
    const int wave = threadIdx.x >> 6;
    const int lg   = lane & 15;
    const int grp  = lane >> 4;
    const int n = (blockIdx.x * 4 + wave) * 4 + grp;
    if (n >= N) return;

    const int t = tgt_ids[n];
    int rows[K + 1];
    rows[0] = ctx_ids[n];
    const int4 n4 = *(const int4*)(neg_ids + (size_t)n * K);
    rows[1] = n4.x; rows[2] = n4.y; rows[3] = n4.z; rows[4] = n4.w;
    rows[5] = neg_ids[(size_t)n * K + 4];

    // One dwordx4 (8 halves) per lane per row: the 16-lane group covers the
    // whole 256 B row in a single coalesced transaction.
    const uint4 in8 = ((const uint4*)(embh + (size_t)t * D))[lg];

    uint4 w8[K + 1];
#pragma unroll
    for (int j = 0; j < K + 1; ++j)
        w8[j] = ((const uint4*)(outh + (size_t)rows[j] * D))[lg];

    float dot[K + 1];
#pragma unroll
    for (int j = 0; j < K + 1; ++j)
        dot[j] = dot8_f16(in8, w8[j], 0.0f);

#pragma unroll
    for (int j = 0; j < K + 1; ++j) {
        float v = dot[j];
        v += __shfl_xor(v, 1);
        v += __shfl_xor(v, 2);
        v += __shfl_xor(v, 4);
        v += __shfl_xor(v, 8);
        dot[j] = v;
    }

    if (lg == 0) {
        float loss = log_sigmoid(dot[0]);
#pragma unroll
        for (int j = 1; j < K + 1; ++j)
            loss += log_sigmoid(-dot[j]);
        out[n] = -loss;
    }
}

// ---- fp32 fallback (R2 kernel) if ws_size too small ----------------------
__global__ __launch_bounds__(256) void sgns_f32_kernel(
    const float* __restrict__ emb,
    const float* __restrict__ out_w,
    const int* __restrict__ tgt_ids,
    const int* __restrict__ ctx_ids,
    const int* __restrict__ neg_ids,
    float* __restrict__ out,
    int N)
{
    const int lane = threadIdx.x & 63;
    const int wave = threadIdx.x >> 6;
    const int lg   = lane & 15;
    const int grp  = lane >> 4;
    const int n = (blockIdx.x * 4 + wave) * 4 + grp;
    if (n >= N) return;

    const int t = tgt_ids[n];
    int rows[K + 1];
    rows[0] = ctx_ids[n];
    const int4 n4 = *(const int4*)(neg_ids + (size_t)n * K);
    rows[1] = n4.x; rows[2] = n4.y; rows[3] = n4.z; rows[4] = n4.w;
    rows[5] = neg_ids[(size_t)n * K + 4];

    const float4* er = (const float4*)(emb + (size_t)t * D);
    const float4 in0 = er[lg];
    const float4 in1 = er[lg + 16];

    float4 w0[K + 1], w1[K + 1];
#pragma unroll
    for (int j = 0; j < K + 1; ++j) {
        const float4* wr = (const float4*)(out_w + (size_t)rows[j] * D);
        w0[j] = wr[lg];
        w1[j] = wr[lg + 16];
    }

    float dot[K + 1];
#pragma unroll
    for (int j = 0; j < K + 1; ++j) {
        dot[j] = in0.x * w0[j].x + in0.y * w0[j].y
               + in0.z * w0[j].z + in0.w * w0[j].w
               + in1.x * w1[j].x + in1.y * w1[j].y
               + in1.z * w1[j].z + in1.w * w1[j].w;
    }

#pragma unroll
    for (int j = 0; j < K + 1; ++j) {
        float v = dot[j];
        v += __shfl_xor(v, 1);
        v += __shfl_xor(v, 2);
        v += __shfl_xor(v, 4);
        v += __shfl_xor(v, 8);
        dot[j] = v;
    }

    if (lg == 0) {
        float loss = log_sigmoid(dot[0]);
#pragma unroll
        for (int j = 1; j < K + 1; ++j)
            loss += log_sigmoid(-dot[j]);
        out[n] = -loss;
    }
}

extern "C" void kernel_launch(void* const* d_in, const int* in_sizes, int n_in,
                              void* d_out, int out_size, void* d_ws, size_t ws_size,
                              hipStream_t stream) {
    const float* emb     = (const float*)d_in[0];
    const float* out_w   = (const float*)d_in[1];
    const int*   tgt_ids = (const int*)d_in[2];
    const int*   ctx_ids = (const int*)d_in[3];
    const int*   neg_ids = (const int*)d_in[4];
    float* out = (float*)d_out;

    const int N = in_sizes[2];                 // 262144 pairs
    const size_t vd = (size_t)in_sizes[0];     // V*D floats per table
    const size_t need = 2 * vd * sizeof(__half);

    const int blocks = (N + 15) / 16;          // 16 pairs per 256-thread block

    if (ws_size >= need) {
        __half* embh = (__half*)d_ws;
        __half* outh = embh + vd;
        const int cvt_threads = (int)(vd / 8);
        const int cvt_blocks = (cvt_threads + 255) / 256;
        cvt_f16_kernel<<<cvt_blocks, 256, 0, stream>>>(emb, embh, (int)vd);
        cvt_f16_kernel<<<cvt_blocks, 256, 0, stream>>>(out_w, outh, (int)vd);
        sgns_f16_kernel<<<blocks, 256, 0, stream>>>(embh, outh, tgt_ids,
                                                    ctx_ids, neg_ids, out, N);
    } else {
        sgns_f32_kernel<<<blocks, 256, 0, stream>>>(emb, out_w, tgt_ids,
                                                    ctx_ids, neg_ids, out, N);
    }
}

// Round 4
// 190.000 us; speedup vs baseline: 1.7990x; 1.0785x over previous
//
#include <hip/hip_runtime.h>
#include <hip/hip_fp16.h>
#include <math.h>

// SGNS (skip-gram negative sampling) loss.  V=100000, D=128, N=262144, K=5.
//
// R4: tables in fp16 (d_ws), gather kernel processes 2 pairs per 16-lane
// group (8 pairs/wave) to double outstanding VMEM loads per wave — R2→R3
// showed the fetch path is MLP/latency-bound (BW fell 3.4->2.7 TB/s when
// in-flight loads dropped). Fused single conversion kernel for both tables.

#define D 128
#define K 5

typedef _Float16 h2 __attribute__((ext_vector_type(2)));

__device__ __forceinline__ float log_sigmoid(float x) {
    // min(x,0) - log(1+exp(-|x|)); fast log/exp — abs err < 1e-6 here.
    return fminf(x, 0.0f) - __logf(1.0f + __expf(-fabsf(x)));
}

__device__ __forceinline__ float dot8_f16(uint4 a, uint4 b, float acc) {
    acc = __builtin_amdgcn_fdot2(__builtin_bit_cast(h2, a.x),
                                 __builtin_bit_cast(h2, b.x), acc, false);
    acc = __builtin_amdgcn_fdot2(__builtin_bit_cast(h2, a.y),
                                 __builtin_bit_cast(h2, b.y), acc, false);
    acc = __builtin_amdgcn_fdot2(__builtin_bit_cast(h2, a.z),
                                 __builtin_bit_cast(h2, b.z), acc, false);
    acc = __builtin_amdgcn_fdot2(__builtin_bit_cast(h2, a.w),
                                 __builtin_bit_cast(h2, b.w), acc, false);
    return acc;
}

// ---- fused fp32 -> fp16 conversion of both tables ------------------------
struct H8 { __half2 a, b, c, d; };

__global__ __launch_bounds__(256) void cvt2_f16_kernel(
    const float* __restrict__ src0, const float* __restrict__ src1,
    __half* __restrict__ dst0, __half* __restrict__ dst1, int n /*floats per table*/)
{
    int i = (blockIdx.x * blockDim.x + threadIdx.x) * 8;
    const float* src = src0;
    __half* dst = dst0;
    if (i >= n) { src = src1; dst = dst1; i -= n; }
    if (i >= n) return;
    float4 x = *(const float4*)(src + i);
    float4 y = *(const float4*)(src + i + 4);
    H8 h;
    h.a = __floats2half2_rn(x.x, x.y);
    h.b = __floats2half2_rn(x.z, x.w);
    h.c = __floats2half2_rn(y.x, y.y);
    h.d = __floats2half2_rn(y.z, y.w);
    *(H8*)(dst + i) = h;
}

// ---- fp16 gather kernel: 16 lanes/pair-slot, 2 pairs per group -----------
__global__ __launch_bounds__(256, 6) void sgns_f16_kernel(
    const __half* __restrict__ embh,
    const __half* __restrict__ outh,
    const int* __restrict__ tgt_ids,
    const int* __restrict__ ctx_ids,
    const int* __restrict__ neg_ids,
    float* __restrict__ out,
    int N)
{
    const int lane = threadIdx.x & 63;
    const int wave = threadIdx.x >> 6;
    const int lg   = lane & 15;
    const int grp  = lane >> 4;
    const int base = (blockIdx.x * 4 + wave) * 8;
    const int n0 = base + grp;        // pair A for this group
    const int n1 = n0 + 4;            // pair B for this group
    if (n1 >= N) {                    // tail (never hit for N=262144)
        if (n0 >= N) return;
    }

    // ---- pair A indices + loads ----
    const int t0 = tgt_ids[n0];
    int rowsA[K + 1];
    rowsA[0] = ctx_ids[n0];
    {
        const int4 n4 = *(const int4*)(neg_ids + (size_t)n0 * K);
        rowsA[1] = n4.x; rowsA[2] = n4.y; rowsA[3] = n4.z; rowsA[4] = n4.w;
        rowsA[5] = neg_ids[(size_t)n0 * K + 4];
    }
    const uint4 inA = ((const uint4*)(embh + (size_t)t0 * D))[lg];
    uint4 wA[K + 1];
#pragma unroll
    for (int j = 0; j < K + 1; ++j)
        wA[j] = ((const uint4*)(outh + (size_t)rowsA[j] * D))[lg];

    // ---- pair B indices + loads (issued before consuming A for MLP) ----
    const int t1 = tgt_ids[n1];
    int rowsB[K + 1];
    rowsB[0] = ctx_ids[n1];
    {
        const int4 n4 = *(const int4*)(neg_ids + (size_t)n1 * K);
        rowsB[1] = n4.x; rowsB[2] = n4.y; rowsB[3] = n4.z; rowsB[4] = n4.w;
        rowsB[5] = neg_ids[(size_t)n1 * K + 4];
    }
    const uint4 inB = ((const uint4*)(embh + (size_t)t1 * D))[lg];
    uint4 wB[K + 1];
#pragma unroll
    for (int j = 0; j < K + 1; ++j)
        wB[j] = ((const uint4*)(outh + (size_t)rowsB[j] * D))[lg];

    // ---- dots + reductions, pair A ----
    float dotA[K + 1], dotB[K + 1];
#pragma unroll
    for (int j = 0; j < K + 1; ++j)
        dotA[j] = dot8_f16(inA, wA[j], 0.0f);
#pragma unroll
    for (int j = 0; j < K + 1; ++j)
        dotB[j] = dot8_f16(inB, wB[j], 0.0f);

#pragma unroll
    for (int j = 0; j < K + 1; ++j) {
        float v = dotA[j];
        v += __shfl_xor(v, 1);
        v += __shfl_xor(v, 2);
        v += __shfl_xor(v, 4);
        v += __shfl_xor(v, 8);
        dotA[j] = v;
        float u = dotB[j];
        u += __shfl_xor(u, 1);
        u += __shfl_xor(u, 2);
        u += __shfl_xor(u, 4);
        u += __shfl_xor(u, 8);
        dotB[j] = u;
    }

    if (lg == 0) {
        float lossA = log_sigmoid(dotA[0]);
        float lossB = log_sigmoid(dotB[0]);
#pragma unroll
        for (int j = 1; j < K + 1; ++j) {
            lossA += log_sigmoid(-dotA[j]);
            lossB += log_sigmoid(-dotB[j]);
        }
        out[n0] = -lossA;
        out[n1] = -lossB;
    }
}

// ---- fp32 fallback if ws_size too small ----------------------------------
__global__ __launch_bounds__(256) void sgns_f32_kernel(
    const float* __restrict__ emb,
    const float* __restrict__ out_w,
    const int* __restrict__ tgt_ids,
    const int* __restrict__ ctx_ids,
    const int* __restrict__ neg_ids,
    float* __restrict__ out,
    int N)
{
    const int lane = threadIdx.x & 63;
    const int wave = threadIdx.x >> 6;
    const int lg   = lane & 15;
    const int grp  = lane >> 4;
    const int n = (blockIdx.x * 4 + wave) * 4 + grp;
    if (n >= N) return;

    const int t = tgt_ids[n];
    int rows[K + 1];
    rows[0] = ctx_ids[n];
    const int4 n4 = *(const int4*)(neg_ids + (size_t)n * K);
    rows[1] = n4.x; rows[2] = n4.y; rows[3] = n4.z; rows[4] = n4.w;
    rows[5] = neg_ids[(size_t)n * K + 4];

    const float4* er = (const float4*)(emb + (size_t)t * D);
    const float4 in0 = er[lg];
    const float4 in1 = er[lg + 16];

    float4 w0[K + 1], w1[K + 1];
#pragma unroll
    for (int j = 0; j < K + 1; ++j) {
        const float4* wr = (const float4*)(out_w + (size_t)rows[j] * D);
        w0[j] = wr[lg];
        w1[j] = wr[lg + 16];
    }

    float dot[K + 1];
#pragma unroll
    for (int j = 0; j < K + 1; ++j) {
        dot[j] = in0.x * w0[j].x + in0.y * w0[j].y
               + in0.z * w0[j].z + in0.w * w0[j].w
               + in1.x * w1[j].x + in1.y * w1[j].y
               + in1.z * w1[j].z + in1.w * w1[j].w;
    }

#pragma unroll
    for (int j = 0; j < K + 1; ++j) {
        float v = dot[j];
        v += __shfl_xor(v, 1);
        v += __shfl_xor(v, 2);
        v += __shfl_xor(v, 4);
        v += __shfl_xor(v, 8);
        dot[j] = v;
    }

    if (lg == 0) {
        float loss = log_sigmoid(dot[0]);
#pragma unroll
        for (int j = 1; j < K + 1; ++j)
            loss += log_sigmoid(-dot[j]);
        out[n] = -loss;
    }
}

extern "C" void kernel_launch(void* const* d_in, const int* in_sizes, int n_in,
                              void* d_out, int out_size, void* d_ws, size_t ws_size,
                              hipStream_t stream) {
    const float* emb     = (const float*)d_in[0];
    const float* out_w   = (const float*)d_in[1];
    const int*   tgt_ids = (const int*)d_in[2];
    const int*   ctx_ids = (const int*)d_in[3];
    const int*   neg_ids = (const int*)d_in[4];
    float* out = (float*)d_out;

    const int N = in_sizes[2];                 // 262144 pairs
    const size_t vd = (size_t)in_sizes[0];     // V*D floats per table
    const size_t need = 2 * vd * sizeof(__half);

    if (ws_size >= need) {
        __half* embh = (__half*)d_ws;
        __half* outh = embh + vd;
        const int cvt_threads = (int)(2 * vd / 8);
        const int cvt_blocks = (cvt_threads + 255) / 256;
        cvt2_f16_kernel<<<cvt_blocks, 256, 0, stream>>>(emb, out_w, embh, outh,
                                                        (int)vd);
        const int blocks = (N + 31) / 32;      // 32 pairs per 256-thread block
        sgns_f16_kernel<<<blocks, 256, 0, stream>>>(embh, outh, tgt_ids,
                                                    ctx_ids, neg_ids, out, N);
    } else {
        const int blocks = (N + 15) / 16;
        sgns_f32_kernel<<<blocks, 256, 0, stream>>>(emb, out_w, tgt_ids,
                                                    ctx_ids, neg_ids, out, N);
    }
}

// Round 5
// 188.801 us; speedup vs baseline: 1.8104x; 1.0063x over previous
//
#include <hip/hip_runtime.h>
#include <hip/hip_fp16.h>
#include <math.h>

// SGNS (skip-gram negative sampling) loss.  V=100000, D=128, N=262144, K=5.
//
// R5: same 2-pairs-per-16-lane-group structure as R4, but force ALL 14 data
// loads into flight before any consumption with a scheduler barrier. R4's
// VGPR_Count=32 proved the compiler sank pair-B loads below pair-A use,
// capping outstanding loads at ~7/wave. The gather is VMEM-latency bound;
// more in-flight misses = more of the 6.3 TB/s path used.

#define D 128
#define K 5

typedef _Float16 h2 __attribute__((ext_vector_type(2)));

__device__ __forceinline__ void sched_fence() {
#if __has_builtin(__builtin_amdgcn_sched_barrier)
    __builtin_amdgcn_sched_barrier(0);   // nothing schedules across this
#else
    asm volatile("" ::: "memory");
#endif
}

__device__ __forceinline__ float log_sigmoid(float x) {
    // min(x,0) - log(1+exp(-|x|)); fast log/exp — abs err < 1e-6 here.
    return fminf(x, 0.0f) - __logf(1.0f + __expf(-fabsf(x)));
}

__device__ __forceinline__ float dot8_f16(uint4 a, uint4 b, float acc) {
    acc = __builtin_amdgcn_fdot2(__builtin_bit_cast(h2, a.x),
                                 __builtin_bit_cast(h2, b.x), acc, false);
    acc = __builtin_amdgcn_fdot2(__builtin_bit_cast(h2, a.y),
                                 __builtin_bit_cast(h2, b.y), acc, false);
    acc = __builtin_amdgcn_fdot2(__builtin_bit_cast(h2, a.z),
                                 __builtin_bit_cast(h2, b.z), acc, false);
    acc = __builtin_amdgcn_fdot2(__builtin_bit_cast(h2, a.w),
                                 __builtin_bit_cast(h2, b.w), acc, false);
    return acc;
}

// ---- fused fp32 -> fp16 conversion of both tables ------------------------
struct H8 { __half2 a, b, c, d; };

__global__ __launch_bounds__(256) void cvt2_f16_kernel(
    const float* __restrict__ src0, const float* __restrict__ src1,
    __half* __restrict__ dst0, __half* __restrict__ dst1, int n /*floats per table*/)
{
    int i = (blockIdx.x * blockDim.x + threadIdx.x) * 8;
    const float* src = src0;
    __half* dst = dst0;
    if (i >= n) { src = src1; dst = dst1; i -= n; }
    if (i >= n) return;
    float4 x = *(const float4*)(src + i);
    float4 y = *(const float4*)(src + i + 4);
    H8 h;
    h.a = __floats2half2_rn(x.x, x.y);
    h.b = __floats2half2_rn(x.z, x.w);
    h.c = __floats2half2_rn(y.x, y.y);
    h.d = __floats2half2_rn(y.z, y.w);
    *(H8*)(dst + i) = h;
}

// ---- fp16 gather kernel: 16 lanes/pair-slot, 2 pairs per group -----------
__global__ __launch_bounds__(256) void sgns_f16_kernel(
    const __half* __restrict__ embh,
    const __half* __restrict__ outh,
    const int* __restrict__ tgt_ids,
    const int* __restrict__ ctx_ids,
    const int* __restrict__ neg_ids,
    float* __restrict__ out,
    int N)
{
    const int lane = threadIdx.x & 63;
    const int wave = threadIdx.x >> 6;
    const int lg   = lane & 15;
    const int grp  = lane >> 4;
    const int base = (blockIdx.x * 4 + wave) * 8;
    const int n0 = base + grp;        // pair A for this group
    const int n1 = n0 + 4;            // pair B for this group
    if (n0 >= N) return;              // N is a multiple of 32; never hit

    // ---- all index loads first (address chain for the data loads) ----
    const int t0 = tgt_ids[n0];
    const int t1 = tgt_ids[n1];
    int rowsA[K + 1], rowsB[K + 1];
    rowsA[0] = ctx_ids[n0];
    rowsB[0] = ctx_ids[n1];
    {
        const int4 a4 = *(const int4*)(neg_ids + (size_t)n0 * K);
        rowsA[1] = a4.x; rowsA[2] = a4.y; rowsA[3] = a4.z; rowsA[4] = a4.w;
        rowsA[5] = neg_ids[(size_t)n0 * K + 4];
        const int4 b4 = *(const int4*)(neg_ids + (size_t)n1 * K);
        rowsB[1] = b4.x; rowsB[2] = b4.y; rowsB[3] = b4.z; rowsB[4] = b4.w;
        rowsB[5] = neg_ids[(size_t)n1 * K + 4];
    }

    // ---- issue ALL 14 data loads, then fence: nothing sinks below here ----
    const uint4 inA = ((const uint4*)(embh + (size_t)t0 * D))[lg];
    const uint4 inB = ((const uint4*)(embh + (size_t)t1 * D))[lg];
    uint4 wA[K + 1], wB[K + 1];
#pragma unroll
    for (int j = 0; j < K + 1; ++j)
        wA[j] = ((const uint4*)(outh + (size_t)rowsA[j] * D))[lg];
#pragma unroll
    for (int j = 0; j < K + 1; ++j)
        wB[j] = ((const uint4*)(outh + (size_t)rowsB[j] * D))[lg];
    sched_fence();

    // ---- dots ----
    float dotA[K + 1], dotB[K + 1];
#pragma unroll
    for (int j = 0; j < K + 1; ++j)
        dotA[j] = dot8_f16(inA, wA[j], 0.0f);
#pragma unroll
    for (int j = 0; j < K + 1; ++j)
        dotB[j] = dot8_f16(inB, wB[j], 0.0f);

    // ---- 16-lane butterfly reductions ----
#pragma unroll
    for (int j = 0; j < K + 1; ++j) {
        float v = dotA[j];
        v += __shfl_xor(v, 1);
        v += __shfl_xor(v, 2);
        v += __shfl_xor(v, 4);
        v += __shfl_xor(v, 8);
        dotA[j] = v;
        float u = dotB[j];
        u += __shfl_xor(u, 1);
        u += __shfl_xor(u, 2);
        u += __shfl_xor(u, 4);
        u += __shfl_xor(u, 8);
        dotB[j] = u;
    }

    if (lg == 0) {
        float lossA = log_sigmoid(dotA[0]);
        float lossB = log_sigmoid(dotB[0]);
#pragma unroll
        for (int j = 1; j < K + 1; ++j) {
            lossA += log_sigmoid(-dotA[j]);
            lossB += log_sigmoid(-dotB[j]);
        }
        out[n0] = -lossA;
        out[n1] = -lossB;
    }
}

// ---- fp32 fallback if ws_size too small ----------------------------------
__global__ __launch_bounds__(256) void sgns_f32_kernel(
    const float* __restrict__ emb,
    const float* __restrict__ out_w,
    const int* __restrict__ tgt_ids,
    const int* __restrict__ ctx_ids,
    const int* __restrict__ neg_ids,
    float* __restrict__ out,
    int N)
{
    const int lane = threadIdx.x & 63;
    const int wave = threadIdx.x >> 6;
    const int lg   = lane & 15;
    const int grp  = lane >> 4;
    const int n = (blockIdx.x * 4 + wave) * 4 + grp;
    if (n >= N) return;

    const int t = tgt_ids[n];
    int rows[K + 1];
    rows[0] = ctx_ids[n];
    const int4 n4 = *(const int4*)(neg_ids + (size_t)n * K);
    rows[1] = n4.x; rows[2] = n4.y; rows[3] = n4.z; rows[4] = n4.w;
    rows[5] = neg_ids[(size_t)n * K + 4];

    const float4* er = (const float4*)(emb + (size_t)t * D);
    const float4 in0 = er[lg];
    const float4 in1 = er[lg + 16];

    float4 w0[K + 1], w1[K + 1];
#pragma unroll
    for (int j = 0; j < K + 1; ++j) {
        const float4* wr = (const float4*)(out_w + (size_t)rows[j] * D);
        w0[j] = wr[lg];
        w1[j] = wr[lg + 16];
    }

    float dot[K + 1];
#pragma unroll
    for (int j = 0; j < K + 1; ++j) {
        dot[j] = in0.x * w0[j].x + in0.y * w0[j].y
               + in0.z * w0[j].z + in0.w * w0[j].w
               + in1.x * w1[j].x + in1.y * w1[j].y
               + in1.z * w1[j].z + in1.w * w1[j].w;
    }

#pragma unroll
    for (int j = 0; j < K + 1; ++j) {
        float v = dot[j];
        v += __shfl_xor(v, 1);
        v += __shfl_xor(v, 2);
        v += __shfl_xor(v, 4);
        v += __shfl_xor(v, 8);
        dot[j] = v;
    }

    if (lg == 0) {
        float loss = log_sigmoid(dot[0]);
#pragma unroll
        for (int j = 1; j < K + 1; ++j)
            loss += log_sigmoid(-dot[j]);
        out[n] = -loss;
    }
}

extern "C" void kernel_launch(void* const* d_in, const int* in_sizes, int n_in,
                              void* d_out, int out_size, void* d_ws, size_t ws_size,
                              hipStream_t stream) {
    const float* emb     = (const float*)d_in[0];
    const float* out_w   = (const float*)d_in[1];
    const int*   tgt_ids = (const int*)d_in[2];
    const int*   ctx_ids = (const int*)d_in[3];
    const int*   neg_ids = (const int*)d_in[4];
    float* out = (float*)d_out;

    const int N = in_sizes[2];                 // 262144 pairs
    const size_t vd = (size_t)in_sizes[0];     // V*D floats per table
    const size_t need = 2 * vd * sizeof(__half);

    if (ws_size >= need) {
        __half* embh = (__half*)d_ws;
        __half* outh = embh + vd;
        const int cvt_threads = (int)(2 * vd / 8);
        const int cvt_blocks = (cvt_threads + 255) / 256;
        cvt2_f16_kernel<<<cvt_blocks, 256, 0, stream>>>(emb, out_w, embh, outh,
                                                        (int)vd);
        const int blocks = (N + 31) / 32;      // 32 pairs per 256-thread block
        sgns_f16_kernel<<<blocks, 256, 0, stream>>>(embh, outh, tgt_ids,
                                                    ctx_ids, neg_ids, out, N);
    } else {
        const int blocks = (N + 15) / 16;
        sgns_f32_kernel<<<blocks, 256, 0, stream>>>(emb, out_w, tgt_ids,
                                                    ctx_ids, neg_ids, out, N);
    }
}